// Round 12
// baseline (101.312 us; speedup 1.0000x reference)
//
#include <hip/hip_runtime.h>
#include <hip/hip_bf16.h>

typedef __bf16 bf16x8 __attribute__((ext_vector_type(8)));
typedef float f32x4 __attribute__((ext_vector_type(4)));
typedef unsigned short ushort8 __attribute__((ext_vector_type(8)));
typedef unsigned short ushort4v __attribute__((ext_vector_type(4)));
typedef unsigned char uchar8 __attribute__((ext_vector_type(8)));

constexpr int M = 128;             // B*T
constexpr int K = 4096;            // IN
constexpr int N = 11008;           // OUT
constexpr int BN = 64;             // N cols per block
constexpr int BK = 32;             // K per step
constexpr int KSPLIT = 4;
constexpr int KBLK = K / KSPLIT;   // 1024
constexpr int NBX = N / BN;        // 172
constexpr long long NW = (long long)N * K;
constexpr int RBLK = 2048;
constexpr size_t MN = (size_t)M * N;
constexpr int SCAP = 4096;         // suspects per prep block (expect ~530)

// a-priori delta estimate: E|N(0,1)| = sqrt(2/pi). Codes quantized with DHAT are
// exact outside the suspect bands whenever |delta/DHAT - 1| <= 0.4% (checked).
constexpr float DHAT = 0.79788456f;

// ws layout (bytes)
constexpr size_t PART_OFF  = 0;                                   // 2048 f32
constexpr size_t DELTA_OFF = 8192;                                // f32 delta
constexpr size_t FLAG_OFF  = 8196;                                // u32 overflow
constexpr size_t XBF_OFF   = 8448;                                // X bf16, 1 MB
constexpr size_t CODE_OFF  = XBF_OFF + (size_t)M * K * 2;         // W codes i8
constexpr size_t SCNT_OFF  = CODE_OFF + (size_t)NW;               // 2048 u32
constexpr size_t SLIST_OFF = SCNT_OFF + RBLK * 4;                 // 2048*4096*8B
constexpr size_t P_OFF     = SLIST_OFF + (size_t)RBLK * SCAP * 8;
constexpr size_t WS_NEED   = P_OFF + KSPLIT * MN * sizeof(float); // ~136 MB
constexpr size_t WS_MIN    = RBLK * sizeof(float);

__device__ __forceinline__ unsigned short f2bf_bits(float f) {
    unsigned int u = __builtin_bit_cast(unsigned int, f);
    u += 0x7FFFu + ((u >> 16) & 1u);            // RNE to bf16
    return (unsigned short)(u >> 16);
}

__device__ __forceinline__ int tern(float w, float inv_d) {
    float q = rintf(w * inv_d);                 // RNE = jnp.round (formula of r5-r11)
    q = fminf(1.f, fmaxf(-1.f, q));
    return (int)q;
}

// ---- k1 prep: |W| partials + X->bf16 + codes(DHAT) + suspect lists ----
template <bool CVT>
__global__ __launch_bounds__(256) void prep(const float* __restrict__ w,
                                            const float* __restrict__ x,
                                            float* __restrict__ partials,
                                            unsigned short* __restrict__ xbf,
                                            char* __restrict__ codes,
                                            unsigned int* __restrict__ scnt,
                                            uint2* __restrict__ slist,
                                            unsigned int* __restrict__ flag)
{
    __shared__ int lcnt;
    __shared__ float red[4];
    const int tid = threadIdx.x;
    if (tid == 0) lcnt = 0;
    __syncthreads();

    const int gtid = blockIdx.x * blockDim.x + tid;
    if (CVT && gtid < M * K / 8) {
        const float4* xp = (const float4*)x + (size_t)gtid * 2;
        float4 a = xp[0], b = xp[1];
        ushort8 o;
        o[0] = f2bf_bits(a.x); o[1] = f2bf_bits(a.y);
        o[2] = f2bf_bits(a.z); o[3] = f2bf_bits(a.w);
        o[4] = f2bf_bits(b.x); o[5] = f2bf_bits(b.y);
        o[6] = f2bf_bits(b.z); o[7] = f2bf_bits(b.w);
        *(ushort8*)(xbf + (size_t)gtid * 8) = o;
    }

    const float inv_dhat = 1.0f / (DHAT + 1e-8f);
    const int n4 = (int)(NW / 4);
    const float4* w4 = (const float4*)w;
    unsigned int* c32 = (unsigned int*)codes;
    uint2* mylist = slist + (size_t)blockIdx.x * SCAP;
    const int stride = gridDim.x * blockDim.x;

    float s0 = 0.f, s1 = 0.f, s2 = 0.f, s3 = 0.f;
    for (int i = gtid; i < n4; i += stride) {
        float4 v = w4[i];
        s0 += fabsf(v.x); s1 += fabsf(v.y); s2 += fabsf(v.z); s3 += fabsf(v.w);
        float vf[4] = {v.x, v.y, v.z, v.w};
        unsigned int pack = 0;
#pragma unroll
        for (int e = 0; e < 4; ++e) {
            float r = vf[e] * inv_dhat;
            int q = tern(vf[e], inv_dhat);
            pack |= ((unsigned int)(unsigned char)(char)q) << (8 * e);
            float ar = fabsf(r);
            if (CVT && (fabsf(ar - 0.5f) < 0.01f || fabsf(ar - 1.5f) < 0.03f)) {
                int p = atomicAdd(&lcnt, 1);
                if (p < SCAP)
                    mylist[p] = make_uint2(4u * i + e, __float_as_uint(vf[e]));
            }
        }
        if (CVT) c32[i] = pack;
    }
    float s = (s0 + s1) + (s2 + s3);
#pragma unroll
    for (int off = 32; off > 0; off >>= 1) s += __shfl_down(s, off, 64);
    if ((tid & 63) == 0) red[tid >> 6] = s;
    __syncthreads();
    if (tid == 0) {
        partials[blockIdx.x] = (red[0] + red[1]) + (red[2] + red[3]);
        if (CVT) {
            scnt[blockIdx.x] = (unsigned int)min(lcnt, SCAP);
            if (lcnt > SCAP) atomicOr(flag, 1u);
        }
    }
}

// ---- k2 patch: delta; re-code suspects exactly (or full recode fallback) ----
__global__ __launch_bounds__(256) void patch(const float* __restrict__ w,
                                             const float* __restrict__ partials,
                                             char* __restrict__ codes,
                                             const unsigned int* __restrict__ scnt,
                                             const uint2* __restrict__ slist,
                                             const unsigned int* __restrict__ flag,
                                             float* __restrict__ dws)
{
    __shared__ float red[4];
    const int tid = threadIdx.x;
    float s = 0.f;
#pragma unroll
    for (int i = 0; i < RBLK / 256; ++i) s += partials[tid + i * 256];
#pragma unroll
    for (int off = 32; off > 0; off >>= 1) s += __shfl_down(s, off, 64);
    if ((tid & 63) == 0) red[tid >> 6] = s;
    __syncthreads();
    const float delta =
        (float)((double)((red[0] + red[1]) + (red[2] + red[3])) / (double)NW + 1e-8);
    if (blockIdx.x == 0 && tid == 0) dws[0] = delta;
    const float inv_delta = 1.0f / delta;

    const bool fullrecode = (*flag != 0u) ||
                            (fabsf(delta / (DHAT + 1e-8f) - 1.f) > 0.004f);
    if (!fullrecode) {
        const int cnt = (int)scnt[blockIdx.x];
        const uint2* mylist = slist + (size_t)blockIdx.x * SCAP;
        for (int j = tid; j < cnt; j += 256) {
            uint2 e = mylist[j];
            codes[e.x] = (char)tern(__uint_as_float(e.y), inv_delta);
        }
    } else {                                    // pathological input: exact recode
        const int n4 = (int)(NW / 4);
        const float4* w4 = (const float4*)w;
        unsigned int* c32 = (unsigned int*)codes;
        const int stride = gridDim.x * blockDim.x;
        for (int i = blockIdx.x * blockDim.x + tid; i < n4; i += stride) {
            float4 v = w4[i];
            float vf[4] = {v.x, v.y, v.z, v.w};
            unsigned int pack = 0;
#pragma unroll
            for (int e = 0; e < 4; ++e)
                pack |= ((unsigned int)(unsigned char)(char)tern(vf[e], inv_delta)) << (8 * e);
            c32[i] = pack;
        }
    }
}

// ---- k3 GEMM: X bf16 + W int8 codes -> bf16 +-1/0; r11 structure ----
// PRE:  grid(172,4), KSTEPS=32, partial out (no bias)
// !PRE: grid(172,1), KSTEPS=128, f32 direct path (small-ws fallback)
template <int KSTEPS, bool PRE>
__global__ __launch_bounds__(256, 4) void bitlinear_gemm(
    const void* __restrict__ Xsrc, const float* __restrict__ W,
    const char* __restrict__ codes, const float* __restrict__ dws,
    const float* __restrict__ bias, const float* __restrict__ partials,
    float* __restrict__ dbase)
{
    constexpr int LDSW = 40;                    // 32 + 8 pad shorts (80 B rows)
    __shared__ __attribute__((aligned(16))) unsigned short xs[2][M * LDSW];
    __shared__ __attribute__((aligned(16))) unsigned short wsm[2][BN * LDSW];
    __shared__ float red[4];

    const int tid = threadIdx.x;
    const int lane = tid & 63;
    const int wid = tid >> 6;
    const int wm = wid >> 1;
    const int wn = wid & 1;
    const int cgrp = lane >> 4;
    const int l15 = lane & 15;
    const int n0 = blockIdx.x * BN;
    const int kk0 = PRE ? blockIdx.y * KBLK : 0;
    const int K4 = K / 4;

    const unsigned short* xb = (const unsigned short*)Xsrc;
    const float4* x4p = (const float4*)Xsrc;
    const float4* w4p = (const float4*)W;

    ushort8 xrA[2], xrB[2];
    float4 xfA[4], xfB[4];
    uchar8 wcA, wcB;                            // PRE: 8 codes/thread
    float4 wrA[2], wrB[2];                      // !PRE

    auto issue_set = [&](int t, ushort8 (&xr)[2], float4 (&xf)[4],
                         uchar8& wc, float4 (&wr)[2]) {
        if constexpr (PRE) {
#pragma unroll
            for (int i = 0; i < 2; ++i) {
                const int j = tid + i * 256;
                xr[i] = *(const ushort8*)(xb + (size_t)(j >> 2) * K + kk0 + t * BK + (j & 3) * 8);
            }
            // 256 slots: row=tid>>2 (64), ch=tid&3 (8 codes)
            wc = *(const uchar8*)(codes + (size_t)(n0 + (tid >> 2)) * K + kk0 + t * BK + (tid & 3) * 8);
        } else {
#pragma unroll
            for (int i = 0; i < 4; ++i) {
                const int j = tid + i * 256;
                xf[i] = x4p[(size_t)(j >> 3) * K4 + (t * BK) / 4 + (j & 7)];
            }
#pragma unroll
            for (int i = 0; i < 2; ++i) {
                const int j = tid + i * 256;
                wr[i] = w4p[(size_t)(n0 + (j >> 3)) * K4 + (t * BK) / 4 + (j & 7)];
            }
        }
    };

    float delta, inv_delta = 0.f;
    if constexpr (PRE) {
        delta = dws[0];
        issue_set(0, xrA, xfA, wcA, wrA);
        if (KSTEPS > 1) issue_set(1, xrB, xfB, wcB, wrB);
    } else {
        float ps[RBLK / 256];
#pragma unroll
        for (int i = 0; i < RBLK / 256; ++i) ps[i] = partials[tid + i * 256];
        issue_set(0, xrA, xfA, wcA, wrA);
        if (KSTEPS > 1) issue_set(1, xrB, xfB, wcB, wrB);
        float s = 0.f;
#pragma unroll
        for (int i = 0; i < RBLK / 256; ++i) s += ps[i];
#pragma unroll
        for (int off = 32; off > 0; off >>= 1) s += __shfl_down(s, off, 64);
        if (lane == 0) red[wid] = s;
        __syncthreads();
        delta = (float)((double)((red[0] + red[1]) + (red[2] + red[3])) /
                        (double)NW + 1e-8);
        inv_delta = 1.0f / delta;
    }

    auto stage_set = [&](int buf, ushort8 (&xr)[2], float4 (&xf)[4],
                         uchar8& wc, float4 (&wr)[2]) {
        if constexpr (PRE) {
#pragma unroll
            for (int i = 0; i < 2; ++i) {
                const int j = tid + i * 256;
                *(ushort8*)&xs[buf][(j >> 2) * LDSW + (j & 3) * 8] = xr[i];
            }
            ushort8 wq;
#pragma unroll
            for (int e = 0; e < 8; ++e) {
                unsigned int b = wc[e];         // {0x00,0x01,0xFF}
                wq[e] = (unsigned short)(((b & 1u) * 0x3F80u) | ((b & 0x80u) << 8));
            }
            *(ushort8*)&wsm[buf][(tid >> 2) * LDSW + (tid & 3) * 8] = wq;
        } else {
#pragma unroll
            for (int i = 0; i < 4; ++i) {
                const int j = tid + i * 256;
                float4 v = xf[i];
                ushort4v o;
                o[0] = f2bf_bits(v.x); o[1] = f2bf_bits(v.y);
                o[2] = f2bf_bits(v.z); o[3] = f2bf_bits(v.w);
                *(ushort4v*)&xs[buf][(j >> 3) * LDSW + (j & 7) * 4] = o;
            }
#pragma unroll
            for (int i = 0; i < 2; ++i) {
                const int j = tid + i * 256;
                float wf[4] = {wr[i].x, wr[i].y, wr[i].z, wr[i].w};
                ushort4v wq;
#pragma unroll
                for (int e = 0; e < 4; ++e)
                    wq[e] = f2bf_bits((float)tern(wf[e], inv_delta));
                *(ushort4v*)&wsm[buf][(j >> 3) * LDSW + (j & 7) * 4] = wq;
            }
        }
    };

    f32x4 acc[4][2] = {};

    auto compute = [&](int buf) {
        const unsigned short* xcur = xs[buf];
        const unsigned short* wcur = wsm[buf];
        bf16x8 afr[4], bfr[2];
#pragma unroll
        for (int f = 0; f < 4; ++f)
            afr[f] = *(const bf16x8*)&xcur[(wm * 64 + f * 16 + l15) * LDSW + cgrp * 8];
#pragma unroll
        for (int g = 0; g < 2; ++g)
            bfr[g] = *(const bf16x8*)&wcur[(wn * 32 + g * 16 + l15) * LDSW + cgrp * 8];
#pragma unroll
        for (int f = 0; f < 4; ++f)
#pragma unroll
            for (int g = 0; g < 2; ++g)
                acc[f][g] = __builtin_amdgcn_mfma_f32_16x16x32_bf16(
                    afr[f], bfr[g], acc[f][g], 0, 0, 0);
    };

    for (int t = 0; t < KSTEPS; t += 2) {
        stage_set(0, xrA, xfA, wcA, wrA);
        if (t + 2 < KSTEPS) issue_set(t + 2, xrA, xfA, wcA, wrA);
        __syncthreads();
        compute(0);
        stage_set(1, xrB, xfB, wcB, wrB);
        if (t + 3 < KSTEPS) issue_set(t + 3, xrB, xfB, wcB, wrB);
        __syncthreads();
        compute(1);
    }

    float* dst = PRE ? dbase + (size_t)blockIdx.y * MN : dbase;
#pragma unroll
    for (int f = 0; f < 4; ++f) {
        const int mrow = wm * 64 + f * 16 + cgrp * 4;
#pragma unroll
        for (int g = 0; g < 2; ++g) {
            const int ocol = n0 + wn * 32 + g * 16 + l15;
            const float bv = PRE ? 0.f : bias[ocol];
#pragma unroll
            for (int r = 0; r < 4; ++r)
                dst[(size_t)(mrow + r) * N + ocol] = delta * acc[f][g][r] + bv;
        }
    }
}

// ---- k4 combine: out = sum_y p_y + bias ----
__global__ __launch_bounds__(256) void combine(const float* __restrict__ p,
                                               const float* __restrict__ bias,
                                               float4* __restrict__ out)
{
    const int i4 = blockIdx.x * blockDim.x + threadIdx.x;
    constexpr int N4 = N / 4;
    if (i4 >= (int)(MN / 4)) return;
    const int col4 = i4 % N4;
    float4 s = *(const float4*)(bias + col4 * 4);
#pragma unroll
    for (int y = 0; y < KSPLIT; ++y) {
        float4 v = ((const float4*)(p + y * MN))[i4];
        s.x += v.x; s.y += v.y; s.z += v.z; s.w += v.w;
    }
    out[i4] = s;
}

extern "C" void kernel_launch(void* const* d_in, const int* in_sizes, int n_in,
                              void* d_out, int out_size, void* d_ws, size_t ws_size,
                              hipStream_t stream) {
    const float* x = (const float*)d_in[0];
    const float* w = (const float*)d_in[1];
    const float* bias = (const float*)d_in[2];
    float* out = (float*)d_out;
    char* wsb = (char*)d_ws;
    float* partials = (float*)(wsb + PART_OFF);
    float* dws = (float*)(wsb + DELTA_OFF);
    unsigned int* flag = (unsigned int*)(wsb + FLAG_OFF);
    unsigned short* xbf = (unsigned short*)(wsb + XBF_OFF);
    char* codes = wsb + CODE_OFF;
    unsigned int* scnt = (unsigned int*)(wsb + SCNT_OFF);
    uint2* slist = (uint2*)(wsb + SLIST_OFF);
    float* pbase = (float*)(wsb + P_OFF);

    if (ws_size >= WS_NEED) {
        hipMemsetAsync(flag, 0, 4, stream);
        prep<true><<<RBLK, 256, 0, stream>>>(w, x, partials, xbf, codes,
                                             scnt, slist, flag);
        patch<<<RBLK, 256, 0, stream>>>(w, partials, codes, scnt, slist, flag, dws);
        bitlinear_gemm<KBLK / BK, true><<<dim3(NBX, KSPLIT), 256, 0, stream>>>(
            xbf, w, codes, dws, bias, partials, pbase);
        combine<<<(int)(MN / 4 + 255) / 256, 256, 0, stream>>>(pbase, bias, (float4*)out);
    } else if (ws_size >= WS_MIN) {
        prep<false><<<RBLK, 256, 0, stream>>>(w, x, partials, xbf, codes,
                                              scnt, slist, flag);
        bitlinear_gemm<K / BK, false><<<dim3(NBX, 1), 256, 0, stream>>>(
            x, w, codes, dws, bias, partials, out);
    }
}